// Round 9
// baseline (343.334 us; speedup 1.0000x reference)
//
#include <hip/hip_runtime.h>
#include <hip/hip_bf16.h>

#if defined(__has_include)
#if __has_include(<rocwmma/rocwmma.hpp>)
#include <rocwmma/rocwmma.hpp>
#define HAVE_ROCWMMA 1
#endif
#endif

#define BB 64
#define TT 1024
#define DD 512
#define NS 24

#define POT_OFF   65536
#define LENS_OFF  1638400
#define TRANS_OFF 1638464

#ifdef HAVE_ROCWMMA
// ---------------------------------------------------------------------------
// Kernel 1 (MFMA): pot = x @ W + b via f16 split-precision matrix cores.
// x,W scaled by 256 and Dekker-split to (hi,lo) f16; pot = (hi*whi + hi*wlo
// + lo*whi) * 2^-16 + bias. Dropped lo*wlo ~1e-5 abs (<< 0.0156 tolerance
// scale). 256 blocks x 256 thr = 1 block/CU, 4 waves; each wave 64 rows =
// 4 M-tiles x 2 N-tiles (N=24 padded to 32), K=512 as 32 steps of 16.
// W split staged once (64KB LDS); x tile [256][16] restaged per k-step.
// Epilogue through LDS pot tile (reuses Wh region) -> same float4 writes.
// ---------------------------------------------------------------------------
__global__ __launch_bounds__(256) void gemm_pot(
    const float* __restrict__ x, const float* __restrict__ W,
    const float* __restrict__ bias, const float* __restrict__ trans,
    const float* __restrict__ lb, const float* __restrict__ rb,
    float* __restrict__ out)
{
  using namespace rocwmma;
  __shared__ float16_t Wh[DD * 32];        // 32 KB (pot tile reuses this)
  __shared__ float16_t Wl[DD * 32];        // 32 KB
  __shared__ float16_t xh[256 * 16];       // 8 KB
  __shared__ float16_t xl[256 * 16];       // 8 KB

  const int tid = threadIdx.x;
  const int w   = tid >> 6;                // wave 0..3
  const size_t rowbase = (size_t)blockIdx.x * 256;

  // stage W split (scaled x256), N padded 24->32 with zeros
#pragma unroll
  for (int i = 0; i < 64; ++i) {
    const int idx = tid + i * 256;
    const int k = idx >> 5, n = idx & 31;
    const float v = (n < NS) ? W[k * NS + n] * 256.0f : 0.0f;
    const float16_t h = (float16_t)v;
    Wh[idx] = h;
    Wl[idx] = (float16_t)(v - (float)h);
  }

  fragment<accumulator, 16, 16, 16, float> acc[4][2];
#pragma unroll
  for (int mi = 0; mi < 4; ++mi)
#pragma unroll
    for (int ni = 0; ni < 2; ++ni) fill_fragment(acc[mi][ni], 0.0f);

  for (int kk = 0; kk < DD; kk += 16) {
    __syncthreads();                       // xh/xl free (and W ready, 1st it)
    {
      const float4* xr4 = (const float4*)(x + (rowbase + tid) * DD + kk);
#pragma unroll
      for (int j4 = 0; j4 < 4; ++j4) {
        const float4 v = xr4[j4];
        const float vv[4] = {v.x, v.y, v.z, v.w};
#pragma unroll
        for (int jj = 0; jj < 4; ++jj) {
          const float s = vv[jj] * 256.0f;
          const float16_t h = (float16_t)s;
          xh[tid * 16 + j4 * 4 + jj] = h;
          xl[tid * 16 + j4 * 4 + jj] = (float16_t)(s - (float)h);
        }
      }
    }
    __syncthreads();                       // tiles ready

    fragment<matrix_b, 16, 16, 16, float16_t, row_major> bh[2], bl2[2];
#pragma unroll
    for (int ni = 0; ni < 2; ++ni) {
      load_matrix_sync(bh[ni],  Wh + kk * 32 + ni * 16, 32);
      load_matrix_sync(bl2[ni], Wl + kk * 32 + ni * 16, 32);
    }
#pragma unroll
    for (int mi = 0; mi < 4; ++mi) {
      fragment<matrix_a, 16, 16, 16, float16_t, row_major> ah, al;
      load_matrix_sync(ah, xh + (w * 64 + mi * 16) * 16, 16);
      load_matrix_sync(al, xl + (w * 64 + mi * 16) * 16, 16);
#pragma unroll
      for (int ni = 0; ni < 2; ++ni) {
        mma_sync(acc[mi][ni], ah, bh[ni],  acc[mi][ni]);
        mma_sync(acc[mi][ni], ah, bl2[ni], acc[mi][ni]);
        mma_sync(acc[mi][ni], al, bh[ni],  acc[mi][ni]);
      }
    }
  }
  __syncthreads();                         // all waves done with Wh/Wl

  float* potl = (float*)Wh;                // [256][32] fp32 = 32 KB, reuse
#pragma unroll
  for (int mi = 0; mi < 4; ++mi)
#pragma unroll
    for (int ni = 0; ni < 2; ++ni)
      store_matrix_sync(potl + (w * 64 + mi * 16) * 32 + ni * 16,
                        acc[mi][ni], 32, mem_row_major);
  __syncthreads();

  {
    const size_t row = rowbase + tid;
    const int t = (int)(row & (TT - 1));
    float o[NS];
#pragma unroll
    for (int n = 0; n < NS; ++n) {
      float v = potl[tid * 32 + n] * (1.0f / 65536.0f) + bias[n];
      o[n] = v;
    }
    if (t == 0) {
#pragma unroll
      for (int n = 0; n < NS; ++n) o[n] += lb[n];
    }
    if (t == TT - 1) {
#pragma unroll
      for (int n = 0; n < NS; ++n) o[n] += rb[n];
    }
    float* po = out + POT_OFF + row * NS;
#pragma unroll
    for (int i = 0; i < 6; ++i)
      *(float4*)(po + i * 4) = make_float4(o[4*i], o[4*i+1], o[4*i+2], o[4*i+3]);
  }

  if (blockIdx.x == 0 && tid < BB) out[LENS_OFF + tid] = (float)TT;
  if (blockIdx.x == 1) {
    for (int i = tid; i < NS * NS; i += 256) out[TRANS_OFF + i] = trans[i];
  }
}
#define GEMM_GRID 256

#else  // !HAVE_ROCWMMA — byte-identical r8 fallback
// ---------------------------------------------------------------------------
// Kernel 1 (VALU fallback): pot = x @ W + b.  (r5/r8 version)
// ---------------------------------------------------------------------------
__global__ __launch_bounds__(256) void gemm_pot(
    const float* __restrict__ x, const float* __restrict__ W,
    const float* __restrict__ bias, const float* __restrict__ trans,
    const float* __restrict__ lb, const float* __restrict__ rb,
    float* __restrict__ out)
{
  __shared__ float wl[DD * NS];
  const int tid = threadIdx.x;
  const int l   = tid & 63;
  const int q   = tid >> 6;
  const int row0 = blockIdx.x * 128 + l;
  const int row1 = row0 + 64;

  {
    const float4* Ws = (const float4*)W;
    float4* Wd = (float4*)wl;
#pragma unroll
    for (int i = 0; i < 12; ++i) Wd[tid + i * 256] = Ws[tid + i * 256];
  }
  __syncthreads();

  const float4* xp0 = (const float4*)(x + (size_t)row0 * DD + q * 128);
  const float4* xp1 = (const float4*)(x + (size_t)row1 * DD + q * 128);

  float acc0[NS], acc1[NS];
#pragma unroll
  for (int nn = 0; nn < NS; ++nn) { acc0[nn] = 0.f; acc1[nn] = 0.f; }

  float4 buf0[4], buf1[4];
#pragma unroll
  for (int i = 0; i < 4; ++i) { buf0[i] = xp0[i]; buf1[i] = xp1[i]; }

#pragma unroll
  for (int f = 0; f < 32; ++f) {
    float4 v0 = buf0[f & 3];
    float4 v1 = buf1[f & 3];
    if (f + 4 < 32) { buf0[f & 3] = xp0[f + 4]; buf1[f & 3] = xp1[f + 4]; }
    const float xj0[4] = {v0.x, v0.y, v0.z, v0.w};
    const float xj1[4] = {v1.x, v1.y, v1.z, v1.w};
#pragma unroll
    for (int j = 0; j < 4; ++j) {
      const int k = q * 128 + f * 4 + j;
      const float4* wr = (const float4*)&wl[k * NS];
      float4 w0 = wr[0], w1 = wr[1], w2 = wr[2], w3 = wr[3], w4 = wr[4], w5 = wr[5];
      const float wv[NS] = {w0.x,w0.y,w0.z,w0.w, w1.x,w1.y,w1.z,w1.w,
                            w2.x,w2.y,w2.z,w2.w, w3.x,w3.y,w3.z,w3.w,
                            w4.x,w4.y,w4.z,w4.w, w5.x,w5.y,w5.z,w5.w};
      const float xv0 = xj0[j];
      const float xv1 = xj1[j];
#pragma unroll
      for (int nn = 0; nn < NS; ++nn) {
        acc0[nn] = fmaf(xv0, wv[nn], acc0[nn]);
        acc1[nn] = fmaf(xv1, wv[nn], acc1[nn]);
      }
    }
  }

  __syncthreads();
  if (q != 0) {
#pragma unroll
    for (int nn = 0; nn < NS; ++nn) {
      wl[((q - 1) * 128 + l)      * 25 + nn] = acc0[nn];
      wl[((q - 1) * 128 + 64 + l) * 25 + nn] = acc1[nn];
    }
  }
  __syncthreads();
  if (q == 0) {
#pragma unroll
    for (int rr = 0; rr < 2; ++rr) {
      float* acc = rr ? acc1 : acc0;
      const int row = rr ? row1 : row0;
      const int slot = rr ? (64 + l) : l;
      const int t = row & (TT - 1);
#pragma unroll
      for (int nn = 0; nn < NS; ++nn)
        acc[nn] += wl[(0 * 128 + slot) * 25 + nn] + wl[(1 * 128 + slot) * 25 + nn]
                 + wl[(2 * 128 + slot) * 25 + nn] + bias[nn];
      if (t == 0) {
#pragma unroll
        for (int nn = 0; nn < NS; ++nn) acc[nn] += lb[nn];
      }
      if (t == TT - 1) {
#pragma unroll
        for (int nn = 0; nn < NS; ++nn) acc[nn] += rb[nn];
      }
      float* po = out + POT_OFF + (size_t)row * NS;
#pragma unroll
      for (int i = 0; i < 6; ++i)
        *(float4*)(po + i * 4) = make_float4(acc[4*i], acc[4*i+1], acc[4*i+2], acc[4*i+3]);
    }
  }

  if (blockIdx.x == 0 && tid < BB) out[LENS_OFF + tid] = (float)TT;
  if (blockIdx.x == 1) {
    for (int i = tid; i < NS * NS; i += 256) out[TRANS_OFF + i] = trans[i];
  }
}
#define GEMM_GRID 512
#endif

__device__ __forceinline__ float m3(float a, float b, float c) {
  return fmaxf(fmaxf(a, b), c);   // clang fuses to v_max3_f32
}

// DPP row rotate (within 16-lane rows); direction handled by runtime probe.
#define RORI(dst, src, J) \
  dst = __builtin_amdgcn_mov_dpp((src), 0x120 + (J), 0xF, 0xF, true)

// ---------------------------------------------------------------------------
// Kernel 2 (fused): scan + bp + backtrace — byte-identical to r8 (112 µs).
// Wave 0: VALU-only permlane/DPP scan at setprio(1), publishes prog every 8
// steps; waves 1..15 chase bp concurrently; chunked backtrace.
// ---------------------------------------------------------------------------
__global__ __launch_bounds__(1024) void viterbi_fused(
    const float* __restrict__ pot, const float* __restrict__ trans,
    float* __restrict__ out_dec)
{
  __shared__ float ps[TT * NS + 8];       // alpha rows 0..1023 (+ tail slack)
  __shared__ unsigned char bl[TT * NS];   // backpointers
  __shared__ float tl[NS * NS];           // trans (for bp-build)
  __shared__ int H[32][NS];
  __shared__ int e[32];
  __shared__ int prog;                    // scan frontier (last final row)

  const int b = blockIdx.x, tid = threadIdx.x;

  if (tid < NS * NS) tl[tid] = trans[tid];
  if (tid == 0) *(volatile int*)&prog = 0;
  __syncthreads();

  if (tid < 64) {
    __builtin_amdgcn_s_setprio(1);
    const int r = tid >> 4;
    const int c = tid & 15;
    const int g = r >> 1;
    const int n = 16 * (r & 1) + c;
    const int nm = (n < NS) ? n : (NS - 1);

    const float* gp = pot + (size_t)b * TT * NS;

    int colv[16];
    colv[0] = c;
    RORI(colv[1],  c, 1);  RORI(colv[2],  c, 2);  RORI(colv[3],  c, 3);
    RORI(colv[4],  c, 4);  RORI(colv[5],  c, 5);  RORI(colv[6],  c, 6);
    RORI(colv[7],  c, 7);  RORI(colv[8],  c, 8);  RORI(colv[9],  c, 9);
    RORI(colv[10], c, 10); RORI(colv[11], c, 11); RORI(colv[12], c, 12);
    RORI(colv[13], c, 13); RORI(colv[14], c, 14); RORI(colv[15], c, 15);

    bool selx;
    {
      auto nr = __builtin_amdgcn_permlane16_swap(n, n, false, false);
      selx = (nr[0] == 16 * g + c);
    }

    float tcr[16];
#pragma unroll
    for (int j = 0; j < 16; ++j) {
      const int m = 16 * g + colv[j];
      tcr[j] = (m < NS) ? trans[m * NS + nm] : -__builtin_inff();
    }

    float ar[16];
#pragma unroll
    for (int j = 0; j < 16; ++j) {
      const int m = 16 * g + colv[j];
      ar[j] = gp[(m < NS) ? m : (NS - 1)];
    }

    ps[n] = gp[nm];

    float pv[8];
#pragma unroll
    for (int u = 0; u < 8; ++u) pv[u] = gp[(1 + u) * NS + nm];

    auto step = [&](int tt, float potv) {
      float sc[16];
#pragma unroll
      for (int j = 0; j < 16; ++j) sc[j] = ar[j] + tcr[j];
      float u0 = m3(sc[0],  sc[1],  sc[2]);
      float u1 = m3(sc[3],  sc[4],  sc[5]);
      float u2 = m3(sc[6],  sc[7],  sc[8]);
      float u3 = m3(sc[9],  sc[10], sc[11]);
      float u4 = m3(sc[12], sc[13], sc[14]);
      float pm = fmaxf(m3(u0, u1, u2), m3(u3, u4, sc[15]));
      auto pr = __builtin_amdgcn_permlane32_swap(
          __float_as_int(pm), __float_as_int(pm), false, false);
      float al = fmaxf(__int_as_float(pr[0]), __int_as_float(pr[1])) + potv;
      ps[tt * NS + n] = al;
      auto qr = __builtin_amdgcn_permlane16_swap(
          __float_as_int(al), __float_as_int(al), false, false);
      int asel = selx ? qr[0] : qr[1];
      ar[0] = __int_as_float(asel);
      int d1, d2, d3, d4, d5, d6, d7, d8, d9, d10, d11, d12, d13, d14, d15;
      RORI(d1,  asel, 1);  ar[1]  = __int_as_float(d1);
      RORI(d2,  asel, 2);  ar[2]  = __int_as_float(d2);
      RORI(d3,  asel, 3);  ar[3]  = __int_as_float(d3);
      RORI(d4,  asel, 4);  ar[4]  = __int_as_float(d4);
      RORI(d5,  asel, 5);  ar[5]  = __int_as_float(d5);
      RORI(d6,  asel, 6);  ar[6]  = __int_as_float(d6);
      RORI(d7,  asel, 7);  ar[7]  = __int_as_float(d7);
      RORI(d8,  asel, 8);  ar[8]  = __int_as_float(d8);
      RORI(d9,  asel, 9);  ar[9]  = __int_as_float(d9);
      RORI(d10, asel, 10); ar[10] = __int_as_float(d10);
      RORI(d11, asel, 11); ar[11] = __int_as_float(d11);
      RORI(d12, asel, 12); ar[12] = __int_as_float(d12);
      RORI(d13, asel, 13); ar[13] = __int_as_float(d13);
      RORI(d14, asel, 14); ar[14] = __int_as_float(d14);
      RORI(d15, asel, 15); ar[15] = __int_as_float(d15);
    };

    for (int t = 1; t + 7 <= TT - 1; t += 8) {
#pragma unroll
      for (int u = 0; u < 8; ++u) {
        const int tt = t + u;
        const float potv = pv[u];
        pv[u] = gp[(tt + 8) * NS + nm];
        step(tt, potv);
      }
      asm volatile("" ::: "memory");
      *(volatile int*)&prog = t + 7;
    }
#pragma unroll
    for (int u = 0; u < 7; ++u) step(1017 + u, pv[u]);
    asm volatile("" ::: "memory");
    *(volatile int*)&prog = TT - 1;
    __builtin_amdgcn_s_setprio(0);
  } else {
    const int w  = tid >> 6;
    const int l  = tid & 63;
    const int t0 = 1 + (w - 1) * 69;
    const int tend = (t0 + 68 < TT - 1) ? (t0 + 68) : (TT - 1);
    const int half = (l >= 24) ? 1 : 0;
    const int n = (l < 24) ? l : ((l < 48) ? (l - 24) : 0);
    float tlc[NS];
#pragma unroll
    for (int m = 0; m < NS; ++m) tlc[m] = tl[m * NS + n];
    for (int ta = t0; ta <= tend; ta += 2) {
      while (*(volatile int*)&prog < ta) __builtin_amdgcn_s_sleep(1);
      asm volatile("" ::: "memory");
      const int tloc = ta + half;
      if (l < 48 && tloc <= tend) {
        const float4* rr = (const float4*)&ps[(tloc - 1) * NS];
        float arr[NS];
#pragma unroll
        for (int i = 0; i < 6; ++i) {
          float4 v = rr[i];
          arr[4*i] = v.x; arr[4*i+1] = v.y; arr[4*i+2] = v.z; arr[4*i+3] = v.w;
        }
        float best = arr[0] + tlc[0];
        int bi = 0;
#pragma unroll
        for (int m = 1; m < NS; ++m) {
          float s = arr[m] + tlc[m];
          bool gg = s > best;
          bi = gg ? m : bi;
          best = gg ? s : best;
        }
        bl[tloc * NS + n] = (unsigned char)bi;
      }
    }
  }
  __syncthreads();

  if (tid < 32 * NS) {
    const int c2 = tid / NS, s = tid % NS;
    int a2 = s;
    int tlo = c2 * 32; if (tlo < 1) tlo = 1;
    for (int t = c2 * 32 + 31; t >= tlo; --t) a2 = bl[t * NS + a2];
    H[c2][s] = a2;
  }
  __syncthreads();

  if (tid == 0) {
    const float* ar = &ps[(TT - 1) * NS];
    float best = ar[0]; int bi = 0;
#pragma unroll
    for (int nn = 1; nn < NS; ++nn) {
      float v = ar[nn];
      if (v > best) { best = v; bi = nn; }
    }
    int tag = bi;
    e[31] = tag;
    for (int c2 = 31; c2 >= 1; --c2) { tag = H[c2][tag]; e[c2 - 1] = tag; }
  }
  __syncthreads();

  if (tid < 32) {
    const int c2 = tid;
    int tag = e[c2];
    float* od = out_dec + (size_t)b * TT;
    od[c2 * 32 + 31] = (float)tag;
    for (int t = c2 * 32 + 30; t >= c2 * 32; --t) {
      tag = bl[(t + 1) * NS + tag];
      od[t] = (float)tag;
    }
  }
}

// ---------------------------------------------------------------------------
extern "C" void kernel_launch(void* const* d_in, const int* in_sizes, int n_in,
                              void* d_out, int out_size, void* d_ws, size_t ws_size,
                              hipStream_t stream)
{
  const float* x     = (const float*)d_in[0];
  const float* W     = (const float*)d_in[1];
  const float* bias  = (const float*)d_in[2];
  const float* trans = (const float*)d_in[3];
  const float* lb    = (const float*)d_in[4];
  const float* rb    = (const float*)d_in[5];
  float* out = (float*)d_out;

  gemm_pot<<<GEMM_GRID, 256, 0, stream>>>(x, W, bias, trans, lb, rb, out);
  viterbi_fused<<<BB, 1024, 0, stream>>>(out + POT_OFF, trans, out);
}